// Round 2
// baseline (2382.197 us; speedup 1.0000x reference)
//
#include <hip/hip_runtime.h>

#define DDIM 1024
#define FFD  4096
#define NE   8
#define NTOK 16384
#define NS   32768
#define EPP  2
#define SPP  (4096 * EPP)      // 8192 slots per pass
#define NPASS (NE / EPP)       // 4

typedef __attribute__((ext_vector_type(8))) short short8;
typedef __attribute__((ext_vector_type(8))) __bf16 bf16x8;
typedef __attribute__((ext_vector_type(4))) float f32x4;

#define AS1(p) ((const __attribute__((address_space(1))) void*)(p))
#define AS3(p) ((__attribute__((address_space(3))) void*)(p))
// 2-way-max bank swizzle: unit = u ^ XS(row)
#define XS(r) ((((r) + ((r) >> 2))) & 3)

static __device__ __forceinline__ unsigned short f2bf(float f) {
    unsigned int u = __builtin_bit_cast(unsigned int, f);
    u += 0x7FFFu + ((u >> 16) & 1u);
    return (unsigned short)(u >> 16);
}
static __device__ __forceinline__ float bf2f(unsigned short b) {
    unsigned int u = ((unsigned int)b) << 16;
    return __builtin_bit_cast(float, u);
}
static __device__ __forceinline__ f32x4 MFMA(bf16x8 a, bf16x8 b, f32x4 c) {
    return __builtin_amdgcn_mfma_f32_16x16x32_bf16(a, b, c, 0, 0, 0);
}

// ---------------- Router: logits + stable top-2 + softmax ----------------
__global__ void router_kernel(const float* __restrict__ x, const float* __restrict__ Wr,
                              int* __restrict__ eidx, float* __restrict__ wflat) {
    const int wave = threadIdx.x >> 6, lane = threadIdx.x & 63;
    const int t = blockIdx.x * 4 + wave;
    const float4* xr = (const float4*)(x + (size_t)t * DDIM);
    float4 xv[4];
#pragma unroll
    for (int j = 0; j < 4; j++) xv[j] = xr[lane + 64 * j];
    float logit[NE];
#pragma unroll
    for (int e = 0; e < NE; e++) {
        const float4* wr = (const float4*)(Wr + (size_t)e * DDIM);
        float s = 0.f;
#pragma unroll
        for (int j = 0; j < 4; j++) {
            float4 wv = wr[lane + 64 * j];
            s += xv[j].x * wv.x + xv[j].y * wv.y + xv[j].z * wv.z + xv[j].w * wv.w;
        }
#pragma unroll
        for (int d = 1; d < 64; d <<= 1) s += __shfl_xor(s, d, 64);
        logit[e] = s;
    }
    if (lane == 0) {
        int i1 = 0; float v1 = logit[0];
#pragma unroll
        for (int e = 1; e < NE; e++) if (logit[e] > v1) { v1 = logit[e]; i1 = e; }
        int i2 = -1; float v2 = 0.f;
#pragma unroll
        for (int e = 0; e < NE; e++) {
            if (e == i1) continue;
            if (i2 < 0 || logit[e] > v2) { v2 = logit[e]; i2 = e; }
        }
        float ed = expf(v2 - v1);
        float inv = 1.f / (1.f + ed);
        eidx[2 * t] = i1;  eidx[2 * t + 1] = i2;
        wflat[2 * t] = inv; wflat[2 * t + 1] = ed * inv;
    }
}

// ---------------- Stable counting sort by expert id (single block) ----------------
__global__ void sort_kernel(const int* __restrict__ eidx, const float* __restrict__ wflat,
                            int* __restrict__ stok, float* __restrict__ swt) {
    __shared__ int cnt[2][256][NE];
    __shared__ int ebase[NE];
    const int tid = threadIdx.x;
    const int base = tid * 128;
    int c[NE] = {0, 0, 0, 0, 0, 0, 0, 0};
    for (int i = 0; i < 128; i++) c[eidx[base + i]]++;
#pragma unroll
    for (int e = 0; e < NE; e++) cnt[0][tid][e] = c[e];
    __syncthreads();
    int pp = 0;
    for (int d = 1; d < 256; d <<= 1) {
        int v[NE];
#pragma unroll
        for (int e = 0; e < NE; e++)
            v[e] = cnt[pp][tid][e] + ((tid >= d) ? cnt[pp][tid - d][e] : 0);
#pragma unroll
        for (int e = 0; e < NE; e++) cnt[pp ^ 1][tid][e] = v[e];
        pp ^= 1;
        __syncthreads();
    }
    if (tid == 0) {
        int acc = 0;
        for (int e = 0; e < NE; e++) { ebase[e] = acc; acc += cnt[pp][255][e]; }
    }
    __syncthreads();
    int excl[NE], run[NE];
#pragma unroll
    for (int e = 0; e < NE; e++) { excl[e] = cnt[pp][tid][e] - c[e]; run[e] = 0; }
    for (int i = 0; i < 128; i++) {
        int s = base + i;
        int e = eidx[s];
        int dst = ebase[e] + excl[e] + run[e]++;
        stok[dst] = s >> 1;
        swt[dst] = wflat[s];
    }
}

// ---------------- Per-pass transpose + hi/lo split of W1/W2 (EPP experts) ----------------
// W1[e]: [D][FF] -> w1h/l [eloc][FF][D];  W2[e]: [FF][D] -> w2h/l [eloc][D][FF]
__global__ void transpose_pass(const float* __restrict__ W1, const float* __restrict__ W2, int e0,
                               unsigned short* __restrict__ w1h, unsigned short* __restrict__ w1l,
                               unsigned short* __restrict__ w2h, unsigned short* __restrict__ w2l) {
    __shared__ float tile[32][33];
    int bid = blockIdx.x;
    const int eloc = bid >> 13;          // 8192 blocks per expert
    int rem = bid & 8191;
    const float* ip; unsigned short *oh, *ol; int R, C, bx, by;
    const size_t WE = (size_t)DDIM * FFD;
    if (rem < 4096) {                     // W1 part: R=1024, C=4096
        R = DDIM; C = FFD;
        bx = rem & 127; by = rem >> 7;
        ip = W1 + (size_t)(e0 + eloc) * WE;
        oh = w1h + eloc * WE; ol = w1l + eloc * WE;
    } else {                              // W2 part: R=4096, C=1024
        rem -= 4096; R = FFD; C = DDIM;
        bx = rem & 31; by = rem >> 5;
        ip = W2 + (size_t)(e0 + eloc) * WE;
        oh = w2h + eloc * WE; ol = w2l + eloc * WE;
    }
    const int tx = threadIdx.x, ty = threadIdx.y;
    const int c0 = bx * 32, r0 = by * 32;
#pragma unroll
    for (int i = 0; i < 4; i++)
        tile[ty + i * 8][tx] = ip[(size_t)(r0 + ty + i * 8) * C + c0 + tx];
    __syncthreads();
#pragma unroll
    for (int i = 0; i < 4; i++) {
        int c = c0 + ty + i * 8;
        float f = tile[tx][ty + i * 8];
        unsigned short h = f2bf(f);
        unsigned short l = f2bf(f - bf2f(h));
        size_t o = (size_t)c * R + r0 + tx;
        oh[o] = h; ol[o] = l;
    }
}

// ---------------- GEMM1: h = gelu(gather(x) @ W1[e]) , split-bf16 ----------------
__launch_bounds__(256, 2)
__global__ void gemm1_kernel(const float* __restrict__ x,
                             const unsigned short* __restrict__ w1h, const unsigned short* __restrict__ w1l,
                             const int* __restrict__ stokP,
                             unsigned short* __restrict__ hhi, unsigned short* __restrict__ hlo) {
    __shared__ __align__(16) char Ah[8192]; __shared__ __align__(16) char Al[8192];
    __shared__ __align__(16) char Bh[8192]; __shared__ __align__(16) char Bl[8192];
    __shared__ int toks[128];
    const int tid = threadIdx.x, lane = tid & 63, wave = tid >> 6;
    const int m0 = blockIdx.y * 128, n0 = blockIdx.x * 128;
    const int le = m0 >> 12;            // local expert within this pass (0..EPP-1)
    if (tid < 128) toks[tid] = stokP[m0 + tid];
    __syncthreads();

    f32x4 acc[4][4] = {};
    const int wm = (wave & 1) * 64, wn = (wave >> 1) * 64;
    const int ar = tid >> 1, ahalf = tid & 1;

    for (int kt = 0; kt < DDIM; kt += 32) {
        // B global->LDS (async DMA; swizzled SOURCE so linear dest == swizzled tile)
#pragma unroll
        for (int i = 0; i < 2; i++) {
            int li = (wave * 2 + i) * 64 + lane;
            int r = li >> 2, u = li & 3;
            int us = u ^ XS(r);
            size_t goff = (size_t)(le * FFD + n0 + r) * DDIM + kt + us * 8;
            __builtin_amdgcn_global_load_lds(AS1(w1h + goff), AS3(Bh + (wave * 2 + i) * 1024), 16, 0, 0);
            __builtin_amdgcn_global_load_lds(AS1(w1l + goff), AS3(Bl + (wave * 2 + i) * 1024), 16, 0, 0);
        }
        // reg-stage A: gather fp32 row, split hi/lo, swizzled ds_write
        {
            const float4* xp = (const float4*)(x + (size_t)toks[ar] * DDIM + kt + ahalf * 16);
            float4 a0 = xp[0], a1 = xp[1], a2 = xp[2], a3 = xp[3];
            float fv[16] = {a0.x, a0.y, a0.z, a0.w, a1.x, a1.y, a1.z, a1.w,
                            a2.x, a2.y, a2.z, a2.w, a3.x, a3.y, a3.z, a3.w};
            union SV { unsigned short u[8]; short8 v; } h0, h1, l0, l1;
#pragma unroll
            for (int i = 0; i < 8; i++) {
                unsigned short hh = f2bf(fv[i]);
                h0.u[i] = hh; l0.u[i] = f2bf(fv[i] - bf2f(hh));
                unsigned short hh2 = f2bf(fv[i + 8]);
                h1.u[i] = hh2; l1.u[i] = f2bf(fv[i + 8] - bf2f(hh2));
            }
            const int u0 = ahalf * 2, xr = XS(ar);
            *(short8*)(Ah + ar * 64 + ((u0 ^ xr) * 16)) = h0.v;
            *(short8*)(Ah + ar * 64 + (((u0 + 1) ^ xr) * 16)) = h1.v;
            *(short8*)(Al + ar * 64 + ((u0 ^ xr) * 16)) = l0.v;
            *(short8*)(Al + ar * 64 + (((u0 + 1) ^ xr) * 16)) = l1.v;
        }
        __syncthreads();

        const int ku = lane >> 4;
        bf16x8 afh[4], afl[4], bfh[4], bfl[4];
#pragma unroll
        for (int mf = 0; mf < 4; mf++) {
            int r = wm + mf * 16 + (lane & 15);
            int off = r * 64 + ((ku ^ XS(r)) * 16);
            afh[mf] = *(const bf16x8*)(Ah + off);
            afl[mf] = *(const bf16x8*)(Al + off);
        }
#pragma unroll
        for (int nf = 0; nf < 4; nf++) {
            int r = wn + nf * 16 + (lane & 15);
            int off = r * 64 + ((ku ^ XS(r)) * 16);
            bfh[nf] = *(const bf16x8*)(Bh + off);
            bfl[nf] = *(const bf16x8*)(Bl + off);
        }
#pragma unroll
        for (int mf = 0; mf < 4; mf++)
#pragma unroll
            for (int nf = 0; nf < 4; nf++) {
                acc[mf][nf] = MFMA(afh[mf], bfh[nf], acc[mf][nf]);
                acc[mf][nf] = MFMA(afh[mf], bfl[nf], acc[mf][nf]);
                acc[mf][nf] = MFMA(afl[mf], bfh[nf], acc[mf][nf]);
            }
        __syncthreads();
    }

    // epilogue: exact gelu, split to hi/lo bf16
    const int r0l = (lane >> 4) * 4, cn = lane & 15;
#pragma unroll
    for (int mf = 0; mf < 4; mf++) {
#pragma unroll
        for (int j = 0; j < 4; j++) {
            int srow = m0 + wm + mf * 16 + r0l + j;
            size_t rb = (size_t)srow * FFD;
#pragma unroll
            for (int nf = 0; nf < 4; nf++) {
                int col = n0 + wn + nf * 16 + cn;
                float v = acc[mf][nf][j];
                float g = 0.5f * v * (1.0f + erff(v * 0.70710678118654752f));
                unsigned short h = f2bf(g);
                unsigned short l = f2bf(g - bf2f(h));
                hhi[rb + col] = h;
                hlo[rb + col] = l;
            }
        }
    }
}

// ---------------- GEMM2: out += sw * (h @ W2[e]) , split-bf16, atomic scatter ----------------
__launch_bounds__(256, 2)
__global__ void gemm2_kernel(const unsigned short* __restrict__ hhi, const unsigned short* __restrict__ hlo,
                             const unsigned short* __restrict__ w2h, const unsigned short* __restrict__ w2l,
                             const int* __restrict__ stokP, const float* __restrict__ swtP,
                             float* __restrict__ out) {
    __shared__ __align__(16) char Ah[8192]; __shared__ __align__(16) char Al[8192];
    __shared__ __align__(16) char Bh[8192]; __shared__ __align__(16) char Bl[8192];
    const int tid = threadIdx.x, lane = tid & 63, wave = tid >> 6;
    const int m0 = blockIdx.y * 128, n0 = blockIdx.x * 128;
    const int le = m0 >> 12;

    f32x4 acc[4][4] = {};
    const int wm = (wave & 1) * 64, wn = (wave >> 1) * 64;

    for (int kt = 0; kt < FFD; kt += 32) {
#pragma unroll
        for (int i = 0; i < 2; i++) {
            int li = (wave * 2 + i) * 64 + lane;
            int r = li >> 2, u = li & 3;
            int us = u ^ XS(r);
            size_t aoff = (size_t)(m0 + r) * FFD + kt + us * 8;
            size_t boff = (size_t)(le * DDIM + n0 + r) * FFD + kt + us * 8;
            __builtin_amdgcn_global_load_lds(AS1(hhi + aoff), AS3(Ah + (wave * 2 + i) * 1024), 16, 0, 0);
            __builtin_amdgcn_global_load_lds(AS1(hlo + aoff), AS3(Al + (wave * 2 + i) * 1024), 16, 0, 0);
            __builtin_amdgcn_global_load_lds(AS1(w2h + boff), AS3(Bh + (wave * 2 + i) * 1024), 16, 0, 0);
            __builtin_amdgcn_global_load_lds(AS1(w2l + boff), AS3(Bl + (wave * 2 + i) * 1024), 16, 0, 0);
        }
        __syncthreads();

        const int ku = lane >> 4;
        bf16x8 afh[4], afl[4], bfh[4], bfl[4];
#pragma unroll
        for (int mf = 0; mf < 4; mf++) {
            int r = wm + mf * 16 + (lane & 15);
            int off = r * 64 + ((ku ^ XS(r)) * 16);
            afh[mf] = *(const bf16x8*)(Ah + off);
            afl[mf] = *(const bf16x8*)(Al + off);
        }
#pragma unroll
        for (int nf = 0; nf < 4; nf++) {
            int r = wn + nf * 16 + (lane & 15);
            int off = r * 64 + ((ku ^ XS(r)) * 16);
            bfh[nf] = *(const bf16x8*)(Bh + off);
            bfl[nf] = *(const bf16x8*)(Bl + off);
        }
#pragma unroll
        for (int mf = 0; mf < 4; mf++)
#pragma unroll
            for (int nf = 0; nf < 4; nf++) {
                acc[mf][nf] = MFMA(afh[mf], bfh[nf], acc[mf][nf]);
                acc[mf][nf] = MFMA(afh[mf], bfl[nf], acc[mf][nf]);
                acc[mf][nf] = MFMA(afl[mf], bfh[nf], acc[mf][nf]);
            }
        __syncthreads();
    }

    // epilogue: weight by sw, scatter-add (atomic: same token can appear in 2 experts of one pass)
    const int r0l = (lane >> 4) * 4, cn = lane & 15;
#pragma unroll
    for (int mf = 0; mf < 4; mf++) {
#pragma unroll
        for (int j = 0; j < 4; j++) {
            int srow = m0 + wm + mf * 16 + r0l + j;
            int tok = stokP[srow];
            float w = swtP[srow];
            float* orow = out + (size_t)tok * DDIM;
#pragma unroll
            for (int nf = 0; nf < 4; nf++) {
                int col = n0 + wn + nf * 16 + cn;
                atomicAdd(orow + col, acc[mf][nf][j] * w);
            }
        }
    }
}

extern "C" void kernel_launch(void* const* d_in, const int* in_sizes, int n_in,
                              void* d_out, int out_size, void* d_ws, size_t ws_size,
                              hipStream_t stream) {
    const float* x  = (const float*)d_in[0];
    const float* Wr = (const float*)d_in[1];
    const float* W1 = (const float*)d_in[2];
    const float* W2 = (const float*)d_in[3];
    float* out = (float*)d_out;

    // workspace layout (~192.5 MiB):
    //   per-pass weights hi/lo: 4 * EPP * 4Mi shorts = 64 MiB
    //   per-pass h hi/lo:       2 * SPP*FFD shorts   = 128 MiB
    const size_t WE = (size_t)DDIM * FFD;        // 4 Mi elems
    const size_t HB = (size_t)SPP * FFD;         // 32 Mi elems
    unsigned short* w1h = (unsigned short*)d_ws;
    unsigned short* w1l = w1h + EPP * WE;
    unsigned short* w2h = w1l + EPP * WE;
    unsigned short* w2l = w2h + EPP * WE;
    unsigned short* hhi = w2l + EPP * WE;
    unsigned short* hlo = hhi + HB;
    int*   eidx = (int*)(hlo + HB);
    float* wfl  = (float*)(eidx + NS);
    int*   stok = (int*)(wfl + NS);
    float* swt  = (float*)(stok + NS);

    hipMemsetAsync(d_out, 0, (size_t)NTOK * DDIM * sizeof(float), stream);
    router_kernel<<<NTOK / 4, 256, 0, stream>>>(x, Wr, eidx, wfl);
    sort_kernel<<<1, 256, 0, stream>>>(eidx, wfl, stok, swt);

    for (int p = 0; p < NPASS; p++) {
        transpose_pass<<<EPP * 8192, dim3(32, 8), 0, stream>>>(W1, W2, p * EPP, w1h, w1l, w2h, w2l);
        gemm1_kernel<<<dim3(FFD / 128, SPP / 128), 256, 0, stream>>>(x, w1h, w1l, stok + p * SPP, hhi, hlo);
        gemm2_kernel<<<dim3(DDIM / 128, SPP / 128), 256, 0, stream>>>(hhi, hlo, w2h, w2l,
                                                                      stok + p * SPP, swt + p * SPP, out);
    }
}